// Round 1
// 1818.711 us; speedup vs baseline: 1.1010x; 1.1010x over previous
//
#include <hip/hip_runtime.h>

#define NE   8
#define TPE  1024
#define HID  2048
#define EXD  4096
#define FF   8192  // 2*EXD

typedef short short8 __attribute__((ext_vector_type(8)));
typedef float f32x4 __attribute__((ext_vector_type(4)));

// fp32 -> bf16 (RNE), two packed into one uint (low = a, high = b)
__device__ __forceinline__ unsigned int pk2bf(float a, float b) {
  unsigned int ua = __float_as_uint(a);
  unsigned int ub = __float_as_uint(b);
  ua = (ua + 0x7fffu + ((ua >> 16) & 1u)) >> 16;
  ub = (ub + 0x7fffu + ((ub >> 16) & 1u)) >> 16;
  return ua | (ub << 16);
}

__device__ __forceinline__ unsigned short f2bf(float a) {
  unsigned int ua = __float_as_uint(a);
  return (unsigned short)((ua + 0x7fffu + ((ua >> 16) & 1u)) >> 16);
}

// async global->LDS, 16B per lane. LDS dest must be wave-uniform base
// (HW writes base + lane*16); global src is per-lane.
__device__ __forceinline__ void gload_lds16(const unsigned short* g, unsigned short* l) {
  typedef __attribute__((address_space(1))) unsigned int GU;
  typedef __attribute__((address_space(3))) unsigned int LU;
  __builtin_amdgcn_global_load_lds((const GU*)g, (LU*)l, 16, 0, 0);
}

// ---------------------------------------------------------------------------
// Prep pass 1: straight fp32 -> bf16 convert (x). 8 elems/thread.
// ---------------------------------------------------------------------------
__global__ __launch_bounds__(256) void convert_bf16(
    const float* __restrict__ in, unsigned short* __restrict__ out, int n8) {
  const int i = blockIdx.x * 256 + threadIdx.x;
  if (i >= n8) return;
  const float4 a0 = *(const float4*)(in + (size_t)i * 8);
  const float4 a1 = *(const float4*)(in + (size_t)i * 8 + 4);
  uint4 p;
  p.x = pk2bf(a0.x, a0.y); p.y = pk2bf(a0.z, a0.w);
  p.z = pk2bf(a1.x, a1.y); p.w = pk2bf(a1.z, a1.w);
  *(uint4*)(out + (size_t)i * 8) = p;
}

// ---------------------------------------------------------------------------
// Prep pass 2: transpose-convert: in [e][R][C] fp32 -> out [e][C][R] bf16.
// 64x64 tile via LDS. Memory-bound by design.
// ---------------------------------------------------------------------------
__global__ __launch_bounds__(256) void transpose_cvt(
    const float* __restrict__ in, unsigned short* __restrict__ out, int R, int C) {
  __shared__ unsigned short lt[64 * 64];
  const int e = blockIdx.z;
  const int r0 = blockIdx.y * 64, c0 = blockIdx.x * 64;
  const int t = threadIdx.x;
  const float* ie = in + (size_t)e * R * C;
  unsigned short* oe = out + (size_t)e * R * C;
  const int ty = t >> 4, tx = t & 15;
  #pragma unroll
  for (int it = 0; it < 2; ++it) {
    const int kr = it * 32 + ty * 2;  // even row pair
    const float* p0 = ie + (size_t)(r0 + kr) * C + c0 + tx * 4;
    const float4 a0 = *(const float4*)p0;
    const float4 a1 = *(const float4*)(p0 + C);
    // lt[c][k], pair (kr, kr+1) packed in one dword (kr even -> aligned)
    *(unsigned int*)&lt[(tx * 4 + 0) * 64 + kr] = pk2bf(a0.x, a1.x);
    *(unsigned int*)&lt[(tx * 4 + 1) * 64 + kr] = pk2bf(a0.y, a1.y);
    *(unsigned int*)&lt[(tx * 4 + 2) * 64 + kr] = pk2bf(a0.z, a1.z);
    *(unsigned int*)&lt[(tx * 4 + 3) * 64 + kr] = pk2bf(a0.w, a1.w);
  }
  __syncthreads();
  const int f = t >> 3, ch = t & 7;  // 8 lanes cover one 128B out row
  #pragma unroll
  for (int p = 0; p < 2; ++p) {
    const int fo = p * 32 + f;
    const uint4 v = *(const uint4*)&lt[fo * 64 + ch * 8];
    *(uint4*)(oe + (size_t)(c0 + fo) * R + r0 + ch * 8) = v;
  }
}

// ---------------------------------------------------------------------------
// GEMM1 (bf16 in, silu-gate fused): gated[e,t,i] = up * silu(gate)
// A = xbf [e*TPE+t][HID] (k-contig), B = w1t [e][FF][HID] (k-contig rows).
// m97 structure: 128x128 tile, BK=32, global_load_lds staging, 4 waves 2x2.
// ---------------------------------------------------------------------------
__global__ __launch_bounds__(256) void gemm1_silu_bf(
    const unsigned short* __restrict__ xbf,
    const unsigned short* __restrict__ w1t,
    unsigned short* __restrict__ gated) {
  __shared__ unsigned short As[128 * 32];
  __shared__ unsigned short Bg[128 * 32];
  __shared__ unsigned short Bu[128 * 32];

  const int e  = blockIdx.z;
  const int t0 = blockIdx.y * 128;
  const int i0 = blockIdx.x * 128;
  const int t  = threadIdx.x;
  const int lane = t & 63, wv = t >> 6, wm = wv & 1, wn = wv >> 1;

  const unsigned short* xA  = xbf + (size_t)(e * TPE + t0) * HID;
  const unsigned short* w1e = w1t + (size_t)e * FF * HID;

  const int srow = lane >> 2;        // lane -> row within 16-row chunk
  const int scol = (lane & 3) * 8;   // lane -> 8-elem (16B) slot within 32-k row

  f32x4 accg[4][4], accu[4][4];
  const f32x4 vzero = {0.f, 0.f, 0.f, 0.f};
  #pragma unroll
  for (int a = 0; a < 4; ++a)
    #pragma unroll
    for (int b = 0; b < 4; ++b) { accg[a][b] = vzero; accu[a][b] = vzero; }

  for (int k0 = 0; k0 < HID; k0 += 32) {
    // each wave stages 32 rows (2 x 16-row chunks) of each of As/Bg/Bu
    #pragma unroll
    for (int c = 0; c < 2; ++c) {
      const int rb = wv * 32 + c * 16;   // wave-uniform chunk base row
      const int r  = rb + srow;          // per-lane row
      gload_lds16(xA  + (size_t)r * HID + k0 + scol,               &As[rb * 32]);
      gload_lds16(w1e + (size_t)(i0 + r) * HID + k0 + scol,        &Bg[rb * 32]);
      gload_lds16(w1e + (size_t)(EXD + i0 + r) * HID + k0 + scol,  &Bu[rb * 32]);
    }
    __syncthreads();

    short8 af[4], bgf[4], buf2[4];
    #pragma unroll
    for (int mi = 0; mi < 4; ++mi)
      af[mi] = *(const short8*)&As[(wm * 64 + mi * 16 + (lane & 15)) * 32 + (lane >> 4) * 8];
    #pragma unroll
    for (int ni = 0; ni < 4; ++ni) {
      const int ro = (wn * 64 + ni * 16 + (lane & 15)) * 32 + (lane >> 4) * 8;
      bgf[ni]  = *(const short8*)&Bg[ro];
      buf2[ni] = *(const short8*)&Bu[ro];
    }
    #pragma unroll
    for (int mi = 0; mi < 4; ++mi)
      #pragma unroll
      for (int ni = 0; ni < 4; ++ni) {
        accg[mi][ni] = __builtin_amdgcn_mfma_f32_16x16x32_bf16(af[mi], bgf[ni], accg[mi][ni], 0, 0, 0);
        accu[mi][ni] = __builtin_amdgcn_mfma_f32_16x16x32_bf16(af[mi], buf2[ni], accu[mi][ni], 0, 0, 0);
      }
    __syncthreads();
  }

  // epilogue: silu-gate, bf16 store. C/D layout: col=lane&15, row=(lane>>4)*4+v
  const int r0 = t0 + wm * 64;
  const int c0 = i0 + wn * 64;
  const int qr = (lane >> 4) * 4, cl = lane & 15;
  #pragma unroll
  for (int mi = 0; mi < 4; ++mi)
    #pragma unroll
    for (int ni = 0; ni < 4; ++ni)
      #pragma unroll
      for (int v = 0; v < 4; ++v) {
        const int r = r0 + mi * 16 + qr + v;
        const int c = c0 + ni * 16 + cl;
        const float g = accg[mi][ni][v];
        const float u = accu[mi][ni][v];
        const float s = g / (1.f + __expf(-g));
        gated[(size_t)(e * TPE + r) * EXD + c] = f2bf(u * s);
      }
}

// ---------------------------------------------------------------------------
// GEMM2 (bf16 in): out[e,t,h] = gated[e,t,:] @ W2t[e][h][:], fp32 out.
// ---------------------------------------------------------------------------
__global__ __launch_bounds__(256) void gemm2_bf(
    const unsigned short* __restrict__ gated,
    const unsigned short* __restrict__ w2t,
    float* __restrict__ out) {
  __shared__ unsigned short As[128 * 32];
  __shared__ unsigned short Bs[128 * 32];

  const int e  = blockIdx.z;
  const int t0 = blockIdx.y * 128;
  const int h0 = blockIdx.x * 128;
  const int t  = threadIdx.x;
  const int lane = t & 63, wv = t >> 6, wm = wv & 1, wn = wv >> 1;

  const unsigned short* Ae  = gated + (size_t)(e * TPE + t0) * EXD;
  const unsigned short* w2e = w2t + (size_t)e * HID * EXD;

  const int srow = lane >> 2;
  const int scol = (lane & 3) * 8;

  f32x4 acc[4][4];
  const f32x4 vzero = {0.f, 0.f, 0.f, 0.f};
  #pragma unroll
  for (int a = 0; a < 4; ++a)
    #pragma unroll
    for (int b = 0; b < 4; ++b) acc[a][b] = vzero;

  for (int k0 = 0; k0 < EXD; k0 += 32) {
    #pragma unroll
    for (int c = 0; c < 2; ++c) {
      const int rb = wv * 32 + c * 16;
      const int r  = rb + srow;
      gload_lds16(Ae  + (size_t)r * EXD + k0 + scol,        &As[rb * 32]);
      gload_lds16(w2e + (size_t)(h0 + r) * EXD + k0 + scol, &Bs[rb * 32]);
    }
    __syncthreads();

    short8 af[4], bfr[4];
    #pragma unroll
    for (int mi = 0; mi < 4; ++mi)
      af[mi] = *(const short8*)&As[(wm * 64 + mi * 16 + (lane & 15)) * 32 + (lane >> 4) * 8];
    #pragma unroll
    for (int ni = 0; ni < 4; ++ni)
      bfr[ni] = *(const short8*)&Bs[(wn * 64 + ni * 16 + (lane & 15)) * 32 + (lane >> 4) * 8];
    #pragma unroll
    for (int mi = 0; mi < 4; ++mi)
      #pragma unroll
      for (int ni = 0; ni < 4; ++ni)
        acc[mi][ni] = __builtin_amdgcn_mfma_f32_16x16x32_bf16(af[mi], bfr[ni], acc[mi][ni], 0, 0, 0);
    __syncthreads();
  }

  const int r0 = t0 + wm * 64;
  const int c0 = h0 + wn * 64;
  const int qr = (lane >> 4) * 4, cl = lane & 15;
  #pragma unroll
  for (int mi = 0; mi < 4; ++mi)
    #pragma unroll
    for (int ni = 0; ni < 4; ++ni)
      #pragma unroll
      for (int v = 0; v < 4; ++v) {
        const int r = r0 + mi * 16 + qr + v;
        const int c = c0 + ni * 16 + cl;
        out[(size_t)(e * TPE + r) * HID + c] = acc[mi][ni][v];
      }
}

// ===========================================================================
// FALLBACK (ws too small): previous passing kernels, unchanged. Worst case
// is neutral (2002 us), never broken.
// ===========================================================================
__global__ __launch_bounds__(256) void gemm1_silu(
    const float* __restrict__ x, const float* __restrict__ w1,
    unsigned short* __restrict__ gated) {
  __shared__ unsigned short As[128 * 32];
  __shared__ unsigned short Bg[128 * 32];
  __shared__ unsigned short Bu[128 * 32];

  const int e  = blockIdx.z;
  const int t0 = blockIdx.y * 128;
  const int i0 = blockIdx.x * 128;
  const int t  = threadIdx.x;
  const int lane = t & 63, wv = t >> 6, wm = wv & 1, wn = wv >> 1;

  const float* xA  = x  + (size_t)(e * TPE + t0) * HID;
  const float* w1e = w1 + (size_t)e * HID * FF;

  const int mA = t >> 1, hA = t & 1;
  const int nB = t & 127, gB = t >> 7;

  f32x4 accg[4][4], accu[4][4];
  const f32x4 vzero = {0.f, 0.f, 0.f, 0.f};
  #pragma unroll
  for (int a = 0; a < 4; ++a)
    #pragma unroll
    for (int b = 0; b < 4; ++b) { accg[a][b] = vzero; accu[a][b] = vzero; }

  for (int k0 = 0; k0 < HID; k0 += 32) {
    {
      const float* ap = xA + (size_t)mA * HID + k0 + hA * 16;
      float4 a0 = *(const float4*)(ap + 0);
      float4 a1 = *(const float4*)(ap + 4);
      float4 a2 = *(const float4*)(ap + 8);
      float4 a3 = *(const float4*)(ap + 12);
      uint4 p0, p1;
      p0.x = pk2bf(a0.x, a0.y); p0.y = pk2bf(a0.z, a0.w);
      p0.z = pk2bf(a1.x, a1.y); p0.w = pk2bf(a1.z, a1.w);
      p1.x = pk2bf(a2.x, a2.y); p1.y = pk2bf(a2.z, a2.w);
      p1.z = pk2bf(a3.x, a3.y); p1.w = pk2bf(a3.z, a3.w);
      *(uint4*)&As[mA * 32 + hA * 16 + 0] = p0;
      *(uint4*)&As[mA * 32 + hA * 16 + 8] = p1;
    }
    #pragma unroll
    for (int it = 0; it < 2; ++it) {
      const int kb = gB * 8 + it * 16;
      const float* bp = w1e + (size_t)(k0 + kb) * FF + i0 + nB;
      float gv[8], uv[8];
      #pragma unroll
      for (int r = 0; r < 8; ++r) {
        gv[r] = bp[(size_t)r * FF];
        uv[r] = bp[(size_t)r * FF + EXD];
      }
      uint4 pg, pu;
      pg.x = pk2bf(gv[0], gv[1]); pg.y = pk2bf(gv[2], gv[3]);
      pg.z = pk2bf(gv[4], gv[5]); pg.w = pk2bf(gv[6], gv[7]);
      pu.x = pk2bf(uv[0], uv[1]); pu.y = pk2bf(uv[2], uv[3]);
      pu.z = pk2bf(uv[4], uv[5]); pu.w = pk2bf(uv[6], uv[7]);
      *(uint4*)&Bg[nB * 32 + kb] = pg;
      *(uint4*)&Bu[nB * 32 + kb] = pu;
    }
    __syncthreads();

    short8 af[4], bgf[4], buf2[4];
    #pragma unroll
    for (int mi = 0; mi < 4; ++mi)
      af[mi] = *(const short8*)&As[(wm * 64 + mi * 16 + (lane & 15)) * 32 + (lane >> 4) * 8];
    #pragma unroll
    for (int ni = 0; ni < 4; ++ni) {
      const int ro = (wn * 64 + ni * 16 + (lane & 15)) * 32 + (lane >> 4) * 8;
      bgf[ni] = *(const short8*)&Bg[ro];
      buf2[ni] = *(const short8*)&Bu[ro];
    }
    #pragma unroll
    for (int mi = 0; mi < 4; ++mi)
      #pragma unroll
      for (int ni = 0; ni < 4; ++ni) {
        accg[mi][ni] = __builtin_amdgcn_mfma_f32_16x16x32_bf16(af[mi], bgf[ni], accg[mi][ni], 0, 0, 0);
        accu[mi][ni] = __builtin_amdgcn_mfma_f32_16x16x32_bf16(af[mi], buf2[ni], accu[mi][ni], 0, 0, 0);
      }
    __syncthreads();
  }

  const int r0 = t0 + wm * 64;
  const int c0 = i0 + wn * 64;
  const int qr = (lane >> 4) * 4, cl = lane & 15;
  #pragma unroll
  for (int mi = 0; mi < 4; ++mi)
    #pragma unroll
    for (int ni = 0; ni < 4; ++ni)
      #pragma unroll
      for (int v = 0; v < 4; ++v) {
        const int r = r0 + mi * 16 + qr + v;
        const int c = c0 + ni * 16 + cl;
        const float g = accg[mi][ni][v];
        const float u = accu[mi][ni][v];
        const float s = g / (1.f + __expf(-g));
        gated[(size_t)(e * TPE + r) * EXD + c] = f2bf(u * s);
      }
}

__global__ __launch_bounds__(256) void gemm2(
    const unsigned short* __restrict__ gated, const float* __restrict__ w2,
    float* __restrict__ out) {
  __shared__ unsigned short As[128 * 32];
  __shared__ unsigned short Bs[128 * 32];

  const int e  = blockIdx.z;
  const int t0 = blockIdx.y * 128;
  const int h0 = blockIdx.x * 128;
  const int t  = threadIdx.x;
  const int lane = t & 63, wv = t >> 6, wm = wv & 1, wn = wv >> 1;

  const unsigned short* Ae = gated + (size_t)(e * TPE + t0) * EXD;
  const float* w2e = w2 + (size_t)e * EXD * HID;

  const int arow = t >> 2, ac8 = (t & 3) * 8;
  const int nB = t & 127, gB = t >> 7;

  f32x4 acc[4][4];
  const f32x4 vzero = {0.f, 0.f, 0.f, 0.f};
  #pragma unroll
  for (int a = 0; a < 4; ++a)
    #pragma unroll
    for (int b = 0; b < 4; ++b) acc[a][b] = vzero;

  for (int k0 = 0; k0 < EXD; k0 += 32) {
    #pragma unroll
    for (int rr = 0; rr < 2; ++rr) {
      const unsigned short* gp = Ae + (size_t)(rr * 64 + arow) * EXD + k0 + ac8;
      *(uint4*)&As[rr * 2048 + t * 8] = *(const uint4*)gp;
    }
    #pragma unroll
    for (int it = 0; it < 2; ++it) {
      const int kb = gB * 8 + it * 16;
      const float* bp = w2e + (size_t)(k0 + kb) * HID + h0 + nB;
      float bv[8];
      #pragma unroll
      for (int r = 0; r < 8; ++r) bv[r] = bp[(size_t)r * HID];
      uint4 pb;
      pb.x = pk2bf(bv[0], bv[1]); pb.y = pk2bf(bv[2], bv[3]);
      pb.z = pk2bf(bv[4], bv[5]); pb.w = pk2bf(bv[6], bv[7]);
      *(uint4*)&Bs[nB * 32 + kb] = pb;
    }
    __syncthreads();

    short8 af[4], bfr[4];
    #pragma unroll
    for (int mi = 0; mi < 4; ++mi)
      af[mi] = *(const short8*)&As[(wm * 64 + mi * 16 + (lane & 15)) * 32 + (lane >> 4) * 8];
    #pragma unroll
    for (int ni = 0; ni < 4; ++ni)
      bfr[ni] = *(const short8*)&Bs[(wn * 64 + ni * 16 + (lane & 15)) * 32 + (lane >> 4) * 8];
    #pragma unroll
    for (int mi = 0; mi < 4; ++mi)
      #pragma unroll
      for (int ni = 0; ni < 4; ++ni)
        acc[mi][ni] = __builtin_amdgcn_mfma_f32_16x16x32_bf16(af[mi], bfr[ni], acc[mi][ni], 0, 0, 0);
    __syncthreads();
  }

  const int r0 = t0 + wm * 64;
  const int c0 = h0 + wn * 64;
  const int qr = (lane >> 4) * 4, cl = lane & 15;
  #pragma unroll
  for (int mi = 0; mi < 4; ++mi)
    #pragma unroll
    for (int ni = 0; ni < 4; ++ni)
      #pragma unroll
      for (int v = 0; v < 4; ++v) {
        const int r = r0 + mi * 16 + qr + v;
        const int c = c0 + ni * 16 + cl;
        out[(size_t)(e * TPE + r) * HID + c] = acc[mi][ni][v];
      }
}

extern "C" void kernel_launch(void* const* d_in, const int* in_sizes, int n_in,
                              void* d_out, int out_size, void* d_ws, size_t ws_size,
                              hipStream_t stream) {
  const float* x  = (const float*)d_in[0];   // [8192, 2048] fp32
  const float* w1 = (const float*)d_in[1];   // [8, 2048, 8192] fp32
  const float* w2 = (const float*)d_in[2];   // [8, 4096, 2048] fp32
  float* out = (float*)d_out;                // [8192, 2048] fp32

  const size_t SZ_XBF = (size_t)NE * TPE * HID * 2;  //  32 MiB
  const size_t SZ_W1T = (size_t)NE * FF  * HID * 2;  // 256 MiB
  const size_t SZ_W2T = (size_t)NE * HID * EXD * 2;  // 128 MiB
  const size_t SZ_G   = (size_t)NE * TPE * EXD * 2;  //  64 MiB
  const size_t REQ = SZ_XBF + SZ_W1T + SZ_W2T + SZ_G;  // 480 MiB

  dim3 blk(256, 1, 1);

  if (ws_size >= REQ) {
    unsigned short* xbf   = (unsigned short*)d_ws;
    unsigned short* w1t   = xbf + SZ_XBF / 2;
    unsigned short* w2t   = w1t + SZ_W1T / 2;
    unsigned short* gated = w2t + SZ_W2T / 2;

    const int n8 = NE * TPE * HID / 8;  // 2M threads
    convert_bf16<<<dim3(n8 / 256, 1, 1), blk, 0, stream>>>(x, xbf, n8);
    transpose_cvt<<<dim3(FF / 64, HID / 64, NE), blk, 0, stream>>>(w1, w1t, HID, FF);
    transpose_cvt<<<dim3(HID / 64, EXD / 64, NE), blk, 0, stream>>>(w2, w2t, EXD, HID);
    gemm1_silu_bf<<<dim3(EXD / 128, TPE / 128, NE), blk, 0, stream>>>(xbf, w1t, gated);
    gemm2_bf<<<dim3(HID / 128, TPE / 128, NE), blk, 0, stream>>>(gated, w2t, out);
  } else {
    unsigned short* gated = (unsigned short*)d_ws;  // 64 MiB
    gemm1_silu<<<dim3(EXD / 128, TPE / 128, NE), blk, 0, stream>>>(x, w1, gated);
    gemm2<<<dim3(HID / 128, TPE / 128, NE), blk, 0, stream>>>(gated, w2, out);
  }
}